// Round 6
// baseline (711.143 us; speedup 1.0000x reference)
//
#include <hip/hip_runtime.h>

#define D 1024
#define NB 8
#define T 4096
#define NBLK 512

typedef float fvec4 __attribute__((ext_vector_type(4)));

// ---- monotonic global barrier (agent scope, all NBLK blocks resident) ----
__device__ __forceinline__ void gbar(unsigned* cnt, unsigned tgt) {
    __syncthreads();
    __threadfence();   // release: writeback my dirty lines (agent scope)
    if (threadIdx.x == 0) {
        __hip_atomic_fetch_add(cnt, 1u, __ATOMIC_RELAXED, __HIP_MEMORY_SCOPE_AGENT);
        while (__hip_atomic_load(cnt, __ATOMIC_RELAXED, __HIP_MEMORY_SCOPE_AGENT) < tgt)
            __builtin_amdgcn_s_sleep(2);
    }
    __syncthreads();
    __threadfence();   // acquire: invalidate stale L1/L2 before consuming
}

// ---- tree level stage (identical math to R4/R5-verified tree_gemm) ----
template <int KCH, int NKC, int KCPREV, int MODE>
__device__ __forceinline__ void tree_stage(int bid, int tid,
                                           const float* __restrict__ gprev,
                                           const float* __restrict__ W,
                                           const float* __restrict__ bias,
                                           const float* __restrict__ bt,
                                           float* __restrict__ gout,
                                           int node_base, int prev_base,
                                           float* fs) {
    int node = bid / NKC;
    int kc = bid % NKC;
    int k0 = kc * KCH;

    for (int idx = tid; idx < KCH * 8; idx += 256) {
        int kk = idx % KCH;
        int b = idx / KCH;
        int k = k0 + kk;
        int col = k & 1023;
        float v;
        if (MODE == 0) {
            float p = 0.f;
#pragma unroll
            for (int tc = 0; tc < 8; ++tc)
                p += gprev[(size_t)((b * 8 + node) * 8 + tc) * D + col];
            v = p * (1.0f / 256.0f);
        } else {
            int src = 2 * node + (k >> 10);
            float p = bias[(size_t)(prev_base + src) * D + col];
#pragma unroll 16
            for (int kcp = 0; kcp < KCPREV; ++kcp)
                p += gprev[(size_t)((src * KCPREV + kcp) * 8 + b) * D + col];
            float u = p - bt[(size_t)(prev_base + src) * D + col];
            v = (u > 0.0f) ? p : 0.0f;
        }
        fs[kk * 8 + b] = v;
    }
    __syncthreads();

    const fvec4* Wp = (const fvec4*)W +
                      ((size_t)(node_base + node) * 2048 + (size_t)k0) * 256 + tid;
    fvec4 acc[8];
#pragma unroll
    for (int b = 0; b < 8; ++b) acc[b] = (fvec4){0.f, 0.f, 0.f, 0.f};
#pragma unroll 4
    for (int kk = 0; kk < KCH; ++kk) {
        fvec4 w = __builtin_nontemporal_load(Wp + (size_t)kk * 256);
#pragma unroll
        for (int b = 0; b < 8; ++b) acc[b] += w * fs[kk * 8 + b];
    }
    fvec4* op = (fvec4*)gout + (size_t)((node * NKC + kc) * 8) * 256 + tid;
#pragma unroll
    for (int b = 0; b < 8; ++b) op[(size_t)b * 256] = acc[b];
}

// ===================== single fused kernel, custom barriers =====================
__global__ void __launch_bounds__(256, 2) mono(const float* __restrict__ x,
                                               const float* __restrict__ W,
                                               const float* __restrict__ bias,
                                               const float* __restrict__ bt,
                                               const float* __restrict__ lw,
                                               const float* __restrict__ lb,
                                               float* __restrict__ out,
                                               unsigned* __restrict__ cnt,
                                               float* __restrict__ lpart,
                                               float* __restrict__ gA,
                                               float* __restrict__ gB,
                                               float* __restrict__ root) {
    __shared__ float smem[512];
    int bid = blockIdx.x;
    int tid = threadIdx.x;

    // ---- S1: leaf partial sums (rows 0..2047 of each batch) ----
    {
        int b = bid >> 6, leaf = (bid >> 3) & 7, tc = bid & 7;
        const fvec4* xp = (const fvec4*)x;
        size_t base = ((size_t)(b * T + leaf * 256 + tc * 32)) * 256 + tid;
        fvec4 acc = {0.f, 0.f, 0.f, 0.f};
#pragma unroll 8
        for (int tt = 0; tt < 32; ++tt)
            acc += xp[base + (size_t)tt * 256];
        ((fvec4*)lpart)[(size_t)((b * 8 + leaf) * 8 + tc) * 256 + tid] = acc;
    }
    gbar(cnt, 1 * NBLK);

    // ---- S2: leaf level (nodes 7..14), mean fused into staging ----
    if (bid < 256)
        tree_stage<64, 32, 8, 0>(bid, tid, lpart, W, bias, bt, gA, 7, 0, smem);
    gbar(cnt, 2 * NBLK);

    // ---- S3: level 2 (nodes 3..6) ----
    if (bid < 256)
        tree_stage<32, 64, 32, 1>(bid, tid, gA, W, bias, bt, gB, 3, 7, smem);
    gbar(cnt, 3 * NBLK);

    // ---- S4: level 1 (nodes 1..2) ----
    if (bid < 256)
        tree_stage<16, 128, 64, 1>(bid, tid, gB, W, bias, bt, gA, 1, 3, smem);
    gbar(cnt, 4 * NBLK);

    // ---- S5: level 0 (node 0) ----
    if (bid < 256)
        tree_stage<8, 256, 128, 1>(bid, tid, gA, W, bias, bt, gB, 0, 1, smem);
    gbar(cnt, 5 * NBLK);

    // ---- S6: root gate: sum 256 k-partials, bias, spike ----
    {
        int b = bid >> 6;
        int colg = bid & 63;
        int c = tid & 15, s = tid >> 4;
        int col = colg * 16 + c;
        float p = 0.f;
#pragma unroll
        for (int kc = s; kc < 256; kc += 16)
            p += gB[(size_t)(kc * 8 + b) * D + col];
        smem[s * 16 + c] = p;
        __syncthreads();
        if (tid < 16) {
            int col2 = colg * 16 + tid;
            float tot = bias[col2];
#pragma unroll
            for (int ss = 0; ss < 16; ++ss) tot += smem[ss * 16 + tid];
            float u = tot - bt[col2];
            root[b * D + col2] = (u > 0.0f) ? tot : 0.0f;
        }
    }
    gbar(cnt, 6 * NBLK);

    // ---- S7: out = layernorm(root[b] + x[row]), wave-per-row, 64 rows/blk ----
    {
        int wv = tid >> 6, lane = tid & 63;
        int b = bid >> 6;
        const fvec4* xp = (const fvec4*)x;
        const fvec4* rp = (const fvec4*)root + b * 256;
        const fvec4* lwp = (const fvec4*)lw;
        const fvec4* lbp = (const fvec4*)lb;
        fvec4 rv[4], lwv[4], lbv[4];
#pragma unroll
        for (int j = 0; j < 4; ++j) {
            rv[j] = rp[j * 64 + lane];
            lwv[j] = lwp[j * 64 + lane];
            lbv[j] = lbp[j * 64 + lane];
        }
        for (int i = 0; i < 16; ++i) {
            int row = bid * 64 + i * 4 + wv;
            fvec4 v[4];
            float s = 0.f, q = 0.f;
#pragma unroll
            for (int j = 0; j < 4; ++j) {
                fvec4 xv = xp[(size_t)row * 256 + j * 64 + lane];
                v[j] = xv + rv[j];
                s += v[j].x + v[j].y + v[j].z + v[j].w;
                q += v[j].x * v[j].x + v[j].y * v[j].y + v[j].z * v[j].z + v[j].w * v[j].w;
            }
#pragma unroll
            for (int off = 32; off; off >>= 1) {
                s += __shfl_xor(s, off);
                q += __shfl_xor(q, off);
            }
            float mean = s * (1.0f / D);
            float var = q * (1.0f / D) - mean * mean;
            float rstd = rsqrtf(var + 1e-5f);
            fvec4* op = (fvec4*)out + (size_t)row * 256;
#pragma unroll
            for (int j = 0; j < 4; ++j) {
                fvec4 o = (v[j] - mean) * rstd * lwv[j] + lbv[j];
                __builtin_nontemporal_store(o, op + j * 64 + lane);
            }
        }
    }
}

// ===================== launcher =====================

extern "C" void kernel_launch(void* const* d_in, const int* in_sizes, int n_in,
                              void* d_out, int out_size, void* d_ws, size_t ws_size,
                              hipStream_t stream) {
    const float* x    = (const float*)d_in[0];
    const float* W    = (const float*)d_in[1];
    const float* bias = (const float*)d_in[2];
    const float* bt   = (const float*)d_in[3];
    const float* lw   = (const float*)d_in[4];
    const float* lb   = (const float*)d_in[5];
    float* out = (float*)d_out;

    // ws layout: counter (256 floats pad) | lpart 512K | gA 2M | gB 2M | root 8K
    float* ws = (float*)d_ws;
    unsigned* cnt = (unsigned*)ws;
    float* lpart = ws + 256;
    float* gA    = lpart + 524288;
    float* gB    = gA + 2097152;
    float* root  = gB + 2097152;

    hipMemsetAsync(cnt, 0, sizeof(unsigned), stream);

    mono<<<NBLK, 256, 0, stream>>>(x, W, bias, bt, lw, lb, out,
                                   cnt, lpart, gA, gB, root);
}

// Round 7
// 127.559 us; speedup vs baseline: 5.5750x; 5.5750x over previous
//
#include <hip/hip_runtime.h>

#define D 1024
#define NB 8
#define T 4096

typedef float fvec4 __attribute__((ext_vector_type(4)));

// ---------------- leaves: partial sums over t-chunks of 32 ----------------
// lpart[b][leaf][tc][col] = sum of 32 rows (rows 0..2047 of each batch)
__global__ void __launch_bounds__(256, 2) leaves_partial(const float* __restrict__ x,
                                                         float* __restrict__ lpart) {
    int bid = blockIdx.x;                  // 512 blocks
    int b = bid >> 6, leaf = (bid >> 3) & 7, tc = bid & 7;
    int tid = threadIdx.x;
    const fvec4* xp = (const fvec4*)x;
    size_t base = ((size_t)(b * T + leaf * 256 + tc * 32)) * 256 + tid;
    fvec4 acc = {0.f, 0.f, 0.f, 0.f};
#pragma unroll 8
    for (int tt = 0; tt < 32; ++tt)
        acc += xp[base + (size_t)tt * 256];
    ((fvec4*)lpart)[(size_t)((b * 8 + leaf) * 8 + tc) * 256 + tid] = acc;
}

// ---------------- fused tree-level GEMM (float4 W loads) ------------------
// grid = NODES*NKC blocks; block (node,kc) computes gout[node][kc][b][col]
// = sum_{k in chunk} fused[b][k] * W[node_base+node][k][col], 4 cols/thread.
// MODE 0: stage = mean of 8 lpart partials (per-thread, VALS=512).
// MODE 1: stage = gate(reduce KCPREV partials) — cooperative when VALS<256.
template <int KCH, int NKC, int KCPREV, int MODE>
__global__ void __launch_bounds__(256, 2) tree_gemm(const float* __restrict__ gprev,
                                                    const float* __restrict__ W,
                                                    const float* __restrict__ bias,
                                                    const float* __restrict__ bt,
                                                    float* __restrict__ gout,
                                                    int node_base, int prev_base) {
    int bid = blockIdx.x;
    int node = bid / NKC;
    int kc = bid % NKC;
    int k0 = kc * KCH;
    int tid = threadIdx.x;

    __shared__ float fs[KCH * 8];
    __shared__ float red[256];

    if (MODE == 0) {
        for (int idx = tid; idx < KCH * 8; idx += 256) {
            int kk = idx % KCH;
            int b = idx / KCH;
            int col = (k0 + kk) & 1023;
            float p = 0.f;
#pragma unroll
            for (int tc = 0; tc < 8; ++tc)
                p += gprev[(size_t)((b * 8 + node) * 8 + tc) * D + col];
            fs[kk * 8 + b] = p * (1.0f / 256.0f);
        }
    } else {
        constexpr int VALS = KCH * 8;                       // staged values
        constexpr int SPL = (VALS >= 256) ? 1 : (256 / VALS);
        constexpr int PER = KCPREV / SPL;
        if (SPL == 1) {
            for (int idx = tid; idx < VALS; idx += 256) {
                int kk = idx % KCH;
                int b = idx / KCH;
                int k = k0 + kk;
                int col = k & 1023;
                int src = 2 * node + (k >> 10);
                float p = bias[(size_t)(prev_base + src) * D + col];
#pragma unroll 16
                for (int kcp = 0; kcp < KCPREV; ++kcp)
                    p += gprev[(size_t)((src * KCPREV + kcp) * 8 + b) * D + col];
                float u = p - bt[(size_t)(prev_base + src) * D + col];
                fs[kk * 8 + b] = (u > 0.0f) ? p : 0.0f;
            }
        } else {
            // VALS*SPL == 256: thread t -> value v = t%VALS, slice part = t/VALS
            int v = tid % VALS;
            int part = tid / VALS;
            int kk = v % KCH;
            int b = v / KCH;
            int k = k0 + kk;
            int col = k & 1023;
            int src = 2 * node + (k >> 10);
            float p = 0.f;
#pragma unroll 8
            for (int kcp = part * PER; kcp < (part + 1) * PER; ++kcp)
                p += gprev[(size_t)((src * KCPREV + kcp) * 8 + b) * D + col];
            red[part * VALS + v] = p;
            __syncthreads();
            if (tid < VALS) {
                float tot = bias[(size_t)(prev_base + src) * D + col];
#pragma unroll
                for (int s = 0; s < SPL; ++s) tot += red[s * VALS + v];
                float u = tot - bt[(size_t)(prev_base + src) * D + col];
                fs[kk * 8 + b] = (u > 0.0f) ? tot : 0.0f;
            }
        }
    }
    __syncthreads();

    const fvec4* Wp = (const fvec4*)W +
                      ((size_t)(node_base + node) * 2048 + (size_t)k0) * 256 + tid;
    fvec4 acc[8];
#pragma unroll
    for (int b = 0; b < 8; ++b) acc[b] = (fvec4){0.f, 0.f, 0.f, 0.f};
#pragma unroll 8
    for (int kk = 0; kk < KCH; ++kk) {
        fvec4 w = __builtin_nontemporal_load(Wp + (size_t)kk * 256);
#pragma unroll
        for (int b = 0; b < 8; ++b) acc[b] += w * fs[kk * 8 + b];
    }
    fvec4* op = (fvec4*)gout + (size_t)((node * NKC + kc) * 8) * 256 + tid;
#pragma unroll
    for (int b = 0; b < 8; ++b) op[(size_t)b * 256] = acc[b];
}

// ---------------- root: reduce level-0 partials, bias, gate ---------------
// gpart = [KC kc][8 b][1024 col]; 512 blocks: (b, 16-col group)
template <int KC>
__global__ void __launch_bounds__(256, 2) root_gate(const float* __restrict__ gpart,
                                                    const float* __restrict__ bias,
                                                    const float* __restrict__ bt,
                                                    float* __restrict__ root) {
    int b = blockIdx.x >> 6;
    int colg = blockIdx.x & 63;
    int tid = threadIdx.x;
    int c = tid & 15, s = tid >> 4;
    int col = colg * 16 + c;
    float p = 0.f;
#pragma unroll 4
    for (int kc = s; kc < KC; kc += 16)
        p += gpart[(size_t)(kc * 8 + b) * D + col];
    __shared__ float sm[256];
    sm[s * 16 + c] = p;
    __syncthreads();
    if (tid < 16) {
        int col2 = colg * 16 + tid;
        float tot = bias[col2];
#pragma unroll
        for (int ss = 0; ss < 16; ++ss) tot += sm[ss * 16 + tid];
        float u = tot - bt[col2];
        root[b * D + col2] = (u > 0.0f) ? tot : 0.0f;
    }
}

// ---------------- final: out = layernorm(root[b] + x[row]) ----------------
// 8192 blocks x 4 rows; one 64-lane wave per row, no __syncthreads.
__global__ void __launch_bounds__(256, 2) add_ln(const float* __restrict__ x,
                                                 const float* __restrict__ root,
                                                 const float* __restrict__ lw,
                                                 const float* __restrict__ lb,
                                                 float* __restrict__ out) {
    int tid = threadIdx.x;
    int wv = tid >> 6, lane = tid & 63;
    int row = blockIdx.x * 4 + wv;
    int b = row >> 12;
    const fvec4* xp = (const fvec4*)x;
    const fvec4* rp = (const fvec4*)root + b * 256;
    const fvec4* lwp = (const fvec4*)lw;
    const fvec4* lbp = (const fvec4*)lb;

    fvec4 rv[4], lwv[4], lbv[4], v[4];
#pragma unroll
    for (int j = 0; j < 4; ++j) {
        rv[j] = rp[j * 64 + lane];
        lwv[j] = lwp[j * 64 + lane];
        lbv[j] = lbp[j * 64 + lane];
    }
    float s = 0.f, q = 0.f;
#pragma unroll
    for (int j = 0; j < 4; ++j) {
        fvec4 xv = __builtin_nontemporal_load(xp + (size_t)row * 256 + j * 64 + lane);
        v[j] = xv + rv[j];
        s += v[j].x + v[j].y + v[j].z + v[j].w;
        q += v[j].x * v[j].x + v[j].y * v[j].y + v[j].z * v[j].z + v[j].w * v[j].w;
    }
#pragma unroll
    for (int off = 32; off; off >>= 1) {
        s += __shfl_xor(s, off);
        q += __shfl_xor(q, off);
    }
    float mean = s * (1.0f / D);
    float var = q * (1.0f / D) - mean * mean;
    float rstd = rsqrtf(var + 1e-5f);
    fvec4* op = (fvec4*)out + (size_t)row * 256;
#pragma unroll
    for (int j = 0; j < 4; ++j) {
        fvec4 o = (v[j] - mean) * rstd * lwv[j] + lbv[j];
        __builtin_nontemporal_store(o, op + j * 64 + lane);
    }
}

// ===================== launcher =====================

extern "C" void kernel_launch(void* const* d_in, const int* in_sizes, int n_in,
                              void* d_out, int out_size, void* d_ws, size_t ws_size,
                              hipStream_t stream) {
    const float* x    = (const float*)d_in[0];
    const float* W    = (const float*)d_in[1];
    const float* bias = (const float*)d_in[2];
    const float* bt   = (const float*)d_in[3];
    const float* lw   = (const float*)d_in[4];
    const float* lb   = (const float*)d_in[5];
    float* out = (float*)d_out;

    float* ws = (float*)d_ws;
    float* lpart = ws;                    // 8*8*8*1024          = 524288 floats
    float* gA    = lpart + 524288;        // 8n*32kc*8b*1024     = 2097152
    float* gB    = gA + 2097152;          // up to 256kc*8b*1024 = 2097152
    float* root  = gB + 2097152;          // 8*1024

    // 1) leaf partial sums (rows 0..2047 of each batch)
    leaves_partial<<<512, 256, 0, stream>>>(x, lpart);

    // 2) tree levels, gate fused into consumer staging; 256 blocks each
    // leaf level (nodes 7..14): mean(lpart) -> gA  [8 nodes x 32 kc, KCH=64]
    tree_gemm<64, 32, 8, 0><<<256, 256, 0, stream>>>(lpart, W, bias, bt, gA, 7, 0);
    // level 2 (nodes 3..6): gate(gA, base 7) -> gB [4 x 64, KCH=32]
    tree_gemm<32, 64, 32, 1><<<256, 256, 0, stream>>>(gA, W, bias, bt, gB, 3, 7);
    // level 1 (nodes 1..2): gate(gB, base 3) -> gA [2 x 128, KCH=16]
    tree_gemm<16, 128, 64, 1><<<256, 256, 0, stream>>>(gB, W, bias, bt, gA, 1, 3);
    // level 0 (node 0): gate(gA, base 1) -> gB     [1 x 256, KCH=8]
    tree_gemm<8, 256, 128, 1><<<256, 256, 0, stream>>>(gA, W, bias, bt, gB, 0, 1);

    // 3) root = gate(bias0 + sum_kc gB, bt0)
    root_gate<256><<<512, 256, 0, stream>>>(gB, bias, bt, root);

    // 4) out = layernorm(root + x)
    add_ln<<<NB * T / 4, 256, 0, stream>>>(x, root, lw, lb, out);
}

// Round 8
// 119.079 us; speedup vs baseline: 5.9720x; 1.0712x over previous
//
#include <hip/hip_runtime.h>

#define D 1024
#define NB 8
#define T 4096

typedef float fvec4 __attribute__((ext_vector_type(4)));

// ---------------- leaves: partial sums over t-chunks of 32 ----------------
// lpart[b][leaf][tc][col] = sum of 32 rows (rows 0..2047 of each batch)
__global__ void __launch_bounds__(256, 2) leaves_partial(const float* __restrict__ x,
                                                         float* __restrict__ lpart) {
    int bid = blockIdx.x;                  // 512 blocks
    int b = bid >> 6, leaf = (bid >> 3) & 7, tc = bid & 7;
    int tid = threadIdx.x;
    const fvec4* xp = (const fvec4*)x;
    size_t base = ((size_t)(b * T + leaf * 256 + tc * 32)) * 256 + tid;
    fvec4 acc = {0.f, 0.f, 0.f, 0.f};
#pragma unroll 8
    for (int tt = 0; tt < 32; ++tt)
        acc += xp[base + (size_t)tt * 256];
    ((fvec4*)lpart)[(size_t)((b * 8 + leaf) * 8 + tc) * 256 + tid] = acc;
}

// ---------------- fused tree-level GEMM (float4 W loads) ------------------
// grid = NODES*NKC blocks; block (node,kc) computes gout[node][kc][b][col]
// = sum_{k in chunk} fused[b][k] * W[node_base+node][k][col], 4 cols/thread.
// MODE 0: stage = mean of 8 lpart partials (per-thread, VALS=512).
// MODE 1: stage = gate(reduce KCPREV partials) — cooperative when VALS<256.
template <int KCH, int NKC, int KCPREV, int MODE>
__global__ void __launch_bounds__(256, 2) tree_gemm(const float* __restrict__ gprev,
                                                    const float* __restrict__ W,
                                                    const float* __restrict__ bias,
                                                    const float* __restrict__ bt,
                                                    float* __restrict__ gout,
                                                    int node_base, int prev_base) {
    int bid = blockIdx.x;
    int node = bid / NKC;
    int kc = bid % NKC;
    int k0 = kc * KCH;
    int tid = threadIdx.x;

    __shared__ float fs[KCH * 8];
    __shared__ float red[256];

    if (MODE == 0) {
        for (int idx = tid; idx < KCH * 8; idx += 256) {
            int kk = idx % KCH;
            int b = idx / KCH;
            int col = (k0 + kk) & 1023;
            float p = 0.f;
#pragma unroll
            for (int tc = 0; tc < 8; ++tc)
                p += gprev[(size_t)((b * 8 + node) * 8 + tc) * D + col];
            fs[kk * 8 + b] = p * (1.0f / 256.0f);
        }
    } else {
        constexpr int VALS = KCH * 8;                       // staged values
        constexpr int SPL = (VALS >= 256) ? 1 : (256 / VALS);
        constexpr int PER = KCPREV / SPL;
        if (SPL == 1) {
            for (int idx = tid; idx < VALS; idx += 256) {
                int kk = idx % KCH;
                int b = idx / KCH;
                int k = k0 + kk;
                int col = k & 1023;
                int src = 2 * node + (k >> 10);
                float p = bias[(size_t)(prev_base + src) * D + col];
#pragma unroll 16
                for (int kcp = 0; kcp < KCPREV; ++kcp)
                    p += gprev[(size_t)((src * KCPREV + kcp) * 8 + b) * D + col];
                float u = p - bt[(size_t)(prev_base + src) * D + col];
                fs[kk * 8 + b] = (u > 0.0f) ? p : 0.0f;
            }
        } else {
            // VALS*SPL == 256: thread t -> value v = t%VALS, slice part = t/VALS
            int v = tid % VALS;
            int part = tid / VALS;
            int kk = v % KCH;
            int b = v / KCH;
            int k = k0 + kk;
            int col = k & 1023;
            int src = 2 * node + (k >> 10);
            float p = 0.f;
#pragma unroll 8
            for (int kcp = part * PER; kcp < (part + 1) * PER; ++kcp)
                p += gprev[(size_t)((src * KCPREV + kcp) * 8 + b) * D + col];
            red[part * VALS + v] = p;
            __syncthreads();
            if (tid < VALS) {
                float tot = bias[(size_t)(prev_base + src) * D + col];
#pragma unroll
                for (int s = 0; s < SPL; ++s) tot += red[s * VALS + v];
                float u = tot - bt[(size_t)(prev_base + src) * D + col];
                fs[kk * 8 + b] = (u > 0.0f) ? tot : 0.0f;
            }
        }
    }
    __syncthreads();

    const fvec4* Wp = (const fvec4*)W +
                      ((size_t)(node_base + node) * 2048 + (size_t)k0) * 256 + tid;
    fvec4 acc[8];
#pragma unroll
    for (int b = 0; b < 8; ++b) acc[b] = (fvec4){0.f, 0.f, 0.f, 0.f};
#pragma unroll 8
    for (int kk = 0; kk < KCH; ++kk) {
        fvec4 w = __builtin_nontemporal_load(Wp + (size_t)kk * 256);
#pragma unroll
        for (int b = 0; b < 8; ++b) acc[b] += w * fs[kk * 8 + b];
    }
    fvec4* op = (fvec4*)gout + (size_t)((node * NKC + kc) * 8) * 256 + tid;
#pragma unroll
    for (int b = 0; b < 8; ++b) op[(size_t)b * 256] = acc[b];
}

// ---------------- root: reduce level-0 partials, bias, gate ---------------
// gpart = [KC kc][8 b][1024 col]; 512 blocks: (b, 16-col group)
template <int KC>
__global__ void __launch_bounds__(256, 2) root_gate(const float* __restrict__ gpart,
                                                    const float* __restrict__ bias,
                                                    const float* __restrict__ bt,
                                                    float* __restrict__ root) {
    int b = blockIdx.x >> 6;
    int colg = blockIdx.x & 63;
    int tid = threadIdx.x;
    int c = tid & 15, s = tid >> 4;
    int col = colg * 16 + c;
    float p = 0.f;
#pragma unroll 4
    for (int kc = s; kc < KC; kc += 16)
        p += gpart[(size_t)(kc * 8 + b) * D + col];
    __shared__ float sm[256];
    sm[s * 16 + c] = p;
    __syncthreads();
    if (tid < 16) {
        int col2 = colg * 16 + tid;
        float tot = bias[col2];
#pragma unroll
        for (int ss = 0; ss < 16; ++ss) tot += sm[ss * 16 + tid];
        float u = tot - bt[col2];
        root[b * D + col2] = (u > 0.0f) ? tot : 0.0f;
    }
}

// ---------------- final: out = layernorm(root[b] + x[row]) ----------------
// 8192 blocks x 4 rows; one 64-lane wave per row, no __syncthreads.
// x loads CACHED (L3 reuse with leaves_partial + across replays); store NT.
__global__ void __launch_bounds__(256, 2) add_ln(const float* __restrict__ x,
                                                 const float* __restrict__ root,
                                                 const float* __restrict__ lw,
                                                 const float* __restrict__ lb,
                                                 float* __restrict__ out) {
    int tid = threadIdx.x;
    int wv = tid >> 6, lane = tid & 63;
    int row = blockIdx.x * 4 + wv;
    int b = row >> 12;
    const fvec4* xp = (const fvec4*)x;
    const fvec4* rp = (const fvec4*)root + b * 256;
    const fvec4* lwp = (const fvec4*)lw;
    const fvec4* lbp = (const fvec4*)lb;

    fvec4 rv[4], lwv[4], lbv[4], v[4];
#pragma unroll
    for (int j = 0; j < 4; ++j) {
        rv[j] = rp[j * 64 + lane];
        lwv[j] = lwp[j * 64 + lane];
        lbv[j] = lbp[j * 64 + lane];
    }
    float s = 0.f, q = 0.f;
#pragma unroll
    for (int j = 0; j < 4; ++j) {
        fvec4 xv = xp[(size_t)row * 256 + j * 64 + lane];
        v[j] = xv + rv[j];
        s += v[j].x + v[j].y + v[j].z + v[j].w;
        q += v[j].x * v[j].x + v[j].y * v[j].y + v[j].z * v[j].z + v[j].w * v[j].w;
    }
#pragma unroll
    for (int off = 32; off; off >>= 1) {
        s += __shfl_xor(s, off);
        q += __shfl_xor(q, off);
    }
    float mean = s * (1.0f / D);
    float var = q * (1.0f / D) - mean * mean;
    float rstd = rsqrtf(var + 1e-5f);
    fvec4* op = (fvec4*)out + (size_t)row * 256;
#pragma unroll
    for (int j = 0; j < 4; ++j) {
        fvec4 o = (v[j] - mean) * rstd * lwv[j] + lbv[j];
        __builtin_nontemporal_store(o, op + j * 64 + lane);
    }
}

// ===================== launcher =====================

extern "C" void kernel_launch(void* const* d_in, const int* in_sizes, int n_in,
                              void* d_out, int out_size, void* d_ws, size_t ws_size,
                              hipStream_t stream) {
    const float* x    = (const float*)d_in[0];
    const float* W    = (const float*)d_in[1];
    const float* bias = (const float*)d_in[2];
    const float* bt   = (const float*)d_in[3];
    const float* lw   = (const float*)d_in[4];
    const float* lb   = (const float*)d_in[5];
    float* out = (float*)d_out;

    float* ws = (float*)d_ws;
    float* lpart = ws;                    // 8*8*8*1024          = 524288 floats
    float* gA    = lpart + 524288;        // 8n*32kc*8b*1024     = 2097152
    float* gB    = gA + 2097152;          // up to 256kc*8b*1024 = 2097152
    float* root  = gB + 2097152;          // 8*1024

    // 1) leaf partial sums (rows 0..2047 of each batch)
    leaves_partial<<<512, 256, 0, stream>>>(x, lpart);

    // 2) tree levels, gate fused into consumer staging; 256 blocks each
    // leaf level (nodes 7..14): mean(lpart) -> gA  [8 nodes x 32 kc, KCH=64]
    tree_gemm<64, 32, 8, 0><<<256, 256, 0, stream>>>(lpart, W, bias, bt, gA, 7, 0);
    // level 2 (nodes 3..6): gate(gA, base 7) -> gB [4 x 64, KCH=32]
    tree_gemm<32, 64, 32, 1><<<256, 256, 0, stream>>>(gA, W, bias, bt, gB, 3, 7);
    // level 1 (nodes 1..2): gate(gB, base 3) -> gA [2 x 128, KCH=16]
    tree_gemm<16, 128, 64, 1><<<256, 256, 0, stream>>>(gB, W, bias, bt, gA, 1, 3);
    // level 0 (node 0): gate(gA, base 1) -> gB     [1 x 256, KCH=8]
    tree_gemm<8, 256, 128, 1><<<256, 256, 0, stream>>>(gA, W, bias, bt, gB, 0, 1);

    // 3) root = gate(bias0 + sum_kc gB, bt0)
    root_gate<256><<<512, 256, 0, stream>>>(gB, bias, bt, root);

    // 4) out = layernorm(root + x)
    add_ln<<<NB * T / 4, 256, 0, stream>>>(x, root, lw, lb, out);
}

// Round 9
// 108.665 us; speedup vs baseline: 6.5444x; 1.0958x over previous
//
#include <hip/hip_runtime.h>

#define D 1024
#define NB 8
#define T 4096

typedef float fvec4 __attribute__((ext_vector_type(4)));

// ---------------- leaves: partial sums over t-chunks of 32 ----------------
// lpart[b][leaf][tc][col] = sum of 32 rows (rows 0..2047 of each batch)
__global__ void __launch_bounds__(256, 2) leaves_partial(const float* __restrict__ x,
                                                         float* __restrict__ lpart) {
    int bid = blockIdx.x;                  // 512 blocks
    int b = bid >> 6, leaf = (bid >> 3) & 7, tc = bid & 7;
    int tid = threadIdx.x;
    const fvec4* xp = (const fvec4*)x;
    size_t base = ((size_t)(b * T + leaf * 256 + tc * 32)) * 256 + tid;
    fvec4 acc = {0.f, 0.f, 0.f, 0.f};
#pragma unroll 8
    for (int tt = 0; tt < 32; ++tt)
        acc += xp[base + (size_t)tt * 256];
    ((fvec4*)lpart)[(size_t)((b * 8 + leaf) * 8 + tc) * 256 + tid] = acc;
}

// ---------------- fused tree-level GEMM (float4 W loads) ------------------
// grid = NODES*NKC blocks; block (node,kc) computes gout[node][kc][b][col]
// = sum_{k in chunk} fused[b][k] * W[node_base+node][k][col], 4 cols/thread.
// MODE 0: stage = mean of 8 lpart partials. MODE 1: stage = gate(reduce prev).
// NOTE: unroll 4 (not 8) — unroll 8 spills VGPRs under (256,2) bounds (R8).
template <int KCH, int NKC, int KCPREV, int MODE>
__global__ void __launch_bounds__(256, 2) tree_gemm(const float* __restrict__ gprev,
                                                    const float* __restrict__ W,
                                                    const float* __restrict__ bias,
                                                    const float* __restrict__ bt,
                                                    float* __restrict__ gout,
                                                    int node_base, int prev_base) {
    int bid = blockIdx.x;
    int node = bid / NKC;
    int kc = bid % NKC;
    int k0 = kc * KCH;
    int tid = threadIdx.x;

    __shared__ float fs[KCH * 8];
    for (int idx = tid; idx < KCH * 8; idx += 256) {
        int kk = idx % KCH;
        int b = idx / KCH;
        int k = k0 + kk;
        int col = k & 1023;
        float v;
        if (MODE == 0) {
            float p = 0.f;
#pragma unroll
            for (int tc = 0; tc < 8; ++tc)
                p += gprev[(size_t)((b * 8 + node) * 8 + tc) * D + col];
            v = p * (1.0f / 256.0f);
        } else {
            int src = 2 * node + (k >> 10);
            float p = bias[(size_t)(prev_base + src) * D + col];
#pragma unroll 16
            for (int kcp = 0; kcp < KCPREV; ++kcp)
                p += gprev[(size_t)((src * KCPREV + kcp) * 8 + b) * D + col];
            float u = p - bt[(size_t)(prev_base + src) * D + col];
            v = (u > 0.0f) ? p : 0.0f;
        }
        fs[kk * 8 + b] = v;
    }
    __syncthreads();

    const fvec4* Wp = (const fvec4*)W +
                      ((size_t)(node_base + node) * 2048 + (size_t)k0) * 256 + tid;
    fvec4 acc[8];
#pragma unroll
    for (int b = 0; b < 8; ++b) acc[b] = (fvec4){0.f, 0.f, 0.f, 0.f};
#pragma unroll 4
    for (int kk = 0; kk < KCH; ++kk) {
        fvec4 w = __builtin_nontemporal_load(Wp + (size_t)kk * 256);
#pragma unroll
        for (int b = 0; b < 8; ++b) acc[b] += w * fs[kk * 8 + b];
    }
    fvec4* op = (fvec4*)gout + (size_t)((node * NKC + kc) * 8) * 256 + tid;
#pragma unroll
    for (int b = 0; b < 8; ++b) op[(size_t)b * 256] = acc[b];
}

// ---------------- root: reduce level-0 partials, bias, gate ---------------
// gpart = [KC kc][8 b][1024 col]; 512 blocks: (b, 16-col group)
template <int KC>
__global__ void __launch_bounds__(256, 2) root_gate(const float* __restrict__ gpart,
                                                    const float* __restrict__ bias,
                                                    const float* __restrict__ bt,
                                                    float* __restrict__ root) {
    int b = blockIdx.x >> 6;
    int colg = blockIdx.x & 63;
    int tid = threadIdx.x;
    int c = tid & 15, s = tid >> 4;
    int col = colg * 16 + c;
    float p = 0.f;
#pragma unroll 4
    for (int kc = s; kc < KC; kc += 16)
        p += gpart[(size_t)(kc * 8 + b) * D + col];
    __shared__ float sm[256];
    sm[s * 16 + c] = p;
    __syncthreads();
    if (tid < 16) {
        int col2 = colg * 16 + tid;
        float tot = bias[col2];
#pragma unroll
        for (int ss = 0; ss < 16; ++ss) tot += sm[ss * 16 + tid];
        float u = tot - bt[col2];
        root[b * D + col2] = (u > 0.0f) ? tot : 0.0f;
    }
}

// ---------------- final: out = layernorm(root[b] + x[row]) ----------------
// 4096 blocks x 8 rows; one wave per row-pair (rows wv, wv+4), params loaded
// once per wave. x loads CACHED (L3 reuse across replays); out stored NT.
__global__ void __launch_bounds__(256, 2) add_ln(const float* __restrict__ x,
                                                 const float* __restrict__ root,
                                                 const float* __restrict__ lw,
                                                 const float* __restrict__ lb,
                                                 float* __restrict__ out) {
    int tid = threadIdx.x;
    int wv = tid >> 6, lane = tid & 63;
    int row0 = blockIdx.x * 8 + wv;        // rows row0, row0+4 (same batch b)
    int b = (blockIdx.x * 8) >> 12;
    const fvec4* xp = (const fvec4*)x;
    const fvec4* rp = (const fvec4*)root + b * 256;
    const fvec4* lwp = (const fvec4*)lw;
    const fvec4* lbp = (const fvec4*)lb;

    fvec4 rv[4], lwv[4], lbv[4];
#pragma unroll
    for (int j = 0; j < 4; ++j) {
        rv[j] = rp[j * 64 + lane];
        lwv[j] = lwp[j * 64 + lane];
        lbv[j] = lbp[j * 64 + lane];
    }
#pragma unroll
    for (int r = 0; r < 2; ++r) {
        int row = row0 + r * 4;
        fvec4 v[4];
        float s = 0.f, q = 0.f;
#pragma unroll
        for (int j = 0; j < 4; ++j) {
            fvec4 xv = xp[(size_t)row * 256 + j * 64 + lane];
            v[j] = xv + rv[j];
            s += v[j].x + v[j].y + v[j].z + v[j].w;
            q += v[j].x * v[j].x + v[j].y * v[j].y + v[j].z * v[j].z + v[j].w * v[j].w;
        }
#pragma unroll
        for (int off = 32; off; off >>= 1) {
            s += __shfl_xor(s, off);
            q += __shfl_xor(q, off);
        }
        float mean = s * (1.0f / D);
        float var = q * (1.0f / D) - mean * mean;
        float rstd = rsqrtf(var + 1e-5f);
        fvec4* op = (fvec4*)out + (size_t)row * 256;
#pragma unroll
        for (int j = 0; j < 4; ++j) {
            fvec4 o = (v[j] - mean) * rstd * lwv[j] + lbv[j];
            __builtin_nontemporal_store(o, op + j * 64 + lane);
        }
    }
}

// ===================== launcher =====================

extern "C" void kernel_launch(void* const* d_in, const int* in_sizes, int n_in,
                              void* d_out, int out_size, void* d_ws, size_t ws_size,
                              hipStream_t stream) {
    const float* x    = (const float*)d_in[0];
    const float* W    = (const float*)d_in[1];
    const float* bias = (const float*)d_in[2];
    const float* bt   = (const float*)d_in[3];
    const float* lw   = (const float*)d_in[4];
    const float* lb   = (const float*)d_in[5];
    float* out = (float*)d_out;

    float* ws = (float*)d_ws;
    float* lpart = ws;                    // 8*8*8*1024          = 524288 floats
    float* gA    = lpart + 524288;        // 8n*32kc*8b*1024     = 2097152
    float* gB    = gA + 2097152;          // up to 256kc*8b*1024 = 2097152
    float* root  = gB + 2097152;          // 8*1024

    // 1) leaf partial sums (rows 0..2047 of each batch)
    leaves_partial<<<512, 256, 0, stream>>>(x, lpart);

    // 2) tree levels, gate fused into consumer staging; 256 blocks each
    // leaf level (nodes 7..14): mean(lpart) -> gA  [8 nodes x 32 kc, KCH=64]
    tree_gemm<64, 32, 8, 0><<<256, 256, 0, stream>>>(lpart, W, bias, bt, gA, 7, 0);
    // level 2 (nodes 3..6): gate(gA, base 7) -> gB [4 x 64, KCH=32]
    tree_gemm<32, 64, 32, 1><<<256, 256, 0, stream>>>(gA, W, bias, bt, gB, 3, 7);
    // level 1 (nodes 1..2): gate(gB, base 3) -> gA [2 x 128, KCH=16]
    tree_gemm<16, 128, 64, 1><<<256, 256, 0, stream>>>(gB, W, bias, bt, gA, 1, 3);
    // level 0 (node 0): gate(gA, base 1) -> gB     [1 x 256, KCH=8]
    tree_gemm<8, 256, 128, 1><<<256, 256, 0, stream>>>(gA, W, bias, bt, gB, 0, 1);

    // 3) root = gate(bias0 + sum_kc gB, bt0)
    root_gate<256><<<512, 256, 0, stream>>>(gB, bias, bt, root);

    // 4) out = layernorm(root + x)
    add_ln<<<NB * T / 8, 256, 0, stream>>>(x, root, lw, lb, out);
}